// Round 13
// baseline (422.147 us; speedup 1.0000x reference)
//
#include <hip/hip_runtime.h>

#define NN 100000
#define NE 1600000
#define DD 64
#define BSH 9
#define BSZ 512                          // nodes per bucket
#define NBKT 196                         // ceil(NN/512)
#define BCAP 16384                       // bkt row capacity (mean 8163, ~91 sigma margin)
#define CHUNK 8192                       // edges per scatter block
#define NCH ((NE + CHUNK - 1) / CHUNK)   // 196
#define CSR2_CAP (NE + 16 * NN + 1024)   // sum of pad16(deg+1)

// ---------------- zero init ----------------

__global__ void k_zero(int* __restrict__ bcur, int* __restrict__ gcur,
                       float* __restrict__ h2s) {
    int t = threadIdx.x;
    if (t < NBKT) bcur[t] = 0;
    if (t == 255) *gcur = 0;
    if (t < DD) h2s[(size_t)NN * DD + t] = 0.f;   // dummy row = 0
}

// ---------------- P1: scatter edges into fixed-cap bucket rows ----------------
// packed = s | (dlocal << 17);  s < 2^17, dlocal < 512. bcur[b] ends as count.

__global__ __launch_bounds__(256) void k_bscat(const int* __restrict__ ei,
                                               int* __restrict__ bcur,
                                               int* __restrict__ bkt) {
    __shared__ int h[NBKT], rbase[NBKT], rcur[NBKT];
    int t = threadIdx.x;
    for (int i = t; i < NBKT; i += 256) h[i] = 0;
    __syncthreads();
    int cb = blockIdx.x * CHUNK;
    int s[32], d[32];
#pragma unroll
    for (int i = 0; i < 32; ++i) {
        int e = cb + t + 256 * i;
        if (e < NE) {
            s[i] = ei[e];
            d[i] = ei[NE + e];
            atomicAdd(&h[d[i] >> BSH], 1);
        } else {
            d[i] = -1;
        }
    }
    __syncthreads();
    for (int i = t; i < NBKT; i += 256) {
        int c = h[i];
        rbase[i] = c ? atomicAdd(&bcur[i], c) : 0;
        rcur[i] = 0;
    }
    __syncthreads();
#pragma unroll
    for (int i = 0; i < 32; ++i) {
        if (d[i] >= 0) {
            int b = d[i] >> BSH;
            int pos = rbase[b] + atomicAdd(&rcur[b], 1);
            bkt[(size_t)b * BCAP + pos] = s[i] | ((d[i] & (BSZ - 1)) << 17);
        }
    }
}

// ---------------- P2: per-bucket count + scan + atomic space reservation + csr2 fill ----

__global__ __launch_bounds__(256) void k_merge(const int* __restrict__ bcur,
                                               const int* __restrict__ bkt,
                                               int* __restrict__ gcur,
                                               int* __restrict__ rbeg,
                                               int* __restrict__ rlen,
                                               double* __restrict__ dis,
                                               int* __restrict__ csr2) {
    __shared__ int cnt[BSZ];
    __shared__ int cur[BSZ];
    __shared__ int s2[256];
    __shared__ int sbase;
    int b = blockIdx.x, t = threadIdx.x;
    cnt[t] = 0; cnt[t + 256] = 0;
    __syncthreads();
    int ec = bcur[b];
    const int* row = bkt + (size_t)b * BCAP;
    for (int j = t; j < ec; j += 256)
        atomicAdd(&cnt[row[j] >> 17], 1);
    __syncthreads();
    int nb = b * BSZ;
    int n0 = nb + 2 * t, n1 = nb + 2 * t + 1;
    int c0 = (n0 < NN) ? cnt[2 * t] : -1;
    int c1 = (n1 < NN) ? cnt[2 * t + 1] : -1;
    int q0 = (c0 >= 0) ? ((c0 + 16) & ~15) : 0;      // pad16(deg+1)
    int q1 = (c1 >= 0) ? ((c1 + 16) & ~15) : 0;
    s2[t] = q0 + q1;
    __syncthreads();
    for (int o = 1; o < 256; o <<= 1) {              // Hillis-Steele inclusive scan
        int v = (t >= o) ? s2[t - o] : 0;
        __syncthreads();
        s2[t] += v;
        __syncthreads();
    }
    if (t == 255) sbase = atomicAdd(gcur, s2[255]);  // reserve csr2 space
    __syncthreads();
    int base = sbase;
    int ex = s2[t] - (q0 + q1);                      // exclusive offset of node n0
    if (c0 >= 0) {
        rbeg[n0] = base + ex; rlen[n0] = q0;
        dis[n0] = 1.0 / sqrt((double)(c0 + 1));
        csr2[base + ex] = n0;                        // self entry
        cur[2 * t] = ex + 1;
    }
    if (c1 >= 0) {
        rbeg[n1] = base + ex + q0; rlen[n1] = q1;
        dis[n1] = 1.0 / sqrt((double)(c1 + 1));
        csr2[base + ex + q0] = n1;
        cur[2 * t + 1] = ex + q0 + 1;
    }
    __syncthreads();
    for (int j = t; j < ec; j += 256) {
        int pk = row[j];
        int pos = base + atomicAdd(&cur[pk >> 17], 1);
        csr2[pos] = pk & 0x1FFFF;
    }
    __syncthreads();
    if (c0 >= 0) { int e0 = ex + q0;      for (int j = cur[2 * t];     j < e0; ++j) csr2[base + j] = NN; }
    if (c1 >= 0) { int e1 = ex + q0 + q1; for (int j = cur[2 * t + 1]; j < e1; ++j) csr2[base + j] = NN; }
}

// ---------------- GEMM: h2s = (in @ W) * dis[row] ----------------
// 64 rows/block. Lane c holds W column c in 64 VGPRs (loaded coalesced, no LDS).
// Wave w computes rows w*16..+15: A row read as wave-uniform ds_read_b128
// broadcasts (conflict-free), 4-way k-split f32 accumulators, f64 dis scale.

__global__ __launch_bounds__(256) void k_gemm(const float* __restrict__ in,
                                              const float* __restrict__ W,
                                              const double* __restrict__ dis,
                                              float* __restrict__ h2s) {
    __shared__ float sIn[64 * 64];       // 16 KB
    int t = threadIdx.x;
    int brow = blockIdx.x * 64;
    int c = t & 63;
    int w = t >> 6;

    float wk[64];
#pragma unroll
    for (int k = 0; k < 64; ++k) wk[k] = W[k * DD + c];   // W column c

#pragma unroll
    for (int i = 0; i < 4; ++i) {
        int idx4 = i * 256 + t;                   // float4 index, 0..1023
        int rr = idx4 >> 4, c4 = idx4 & 15;
        int gr = brow + rr; if (gr >= NN) gr = NN - 1;    // clamp (last block)
        *(float4*)&sIn[rr * 64 + c4 * 4] =
            *(const float4*)&in[(size_t)gr * DD + c4 * 4];
    }
    __syncthreads();

    const float* base = &sIn[(w * 16) * 64];
#pragma unroll 2
    for (int r = 0; r < 16; ++r) {
        const float4* row4 = (const float4*)&base[r * 64];
        float a0 = 0.f, a1 = 0.f, a2 = 0.f, a3 = 0.f;
#pragma unroll
        for (int kb = 0; kb < 16; ++kb) {
            float4 av = row4[kb];                 // wave-uniform -> LDS broadcast
            a0 = fmaf(av.x, wk[kb * 4 + 0], a0);
            a1 = fmaf(av.y, wk[kb * 4 + 1], a1);
            a2 = fmaf(av.z, wk[kb * 4 + 2], a2);
            a3 = fmaf(av.w, wk[kb * 4 + 3], a3);
        }
        int row = brow + w * 16 + r;
        if (row < NN) {
            double dr = dis[row];
            h2s[(size_t)row * DD + c] =
                (float)((double)((a0 + a1) + (a2 + a3)) * dr);
        }
    }
}

// ---------------- gather-aggregate: lane = feature, 16 gathers in flight ----------------

__global__ __launch_bounds__(256) void k_aggr(const int* __restrict__ rbeg,
                                              const int* __restrict__ rlen,
                                              const int* __restrict__ csr2,
                                              const float* __restrict__ h2s,
                                              const double* __restrict__ dis,
                                              const float* __restrict__ b,
                                              float* __restrict__ out,
                                              int apply_elu) {
    int gid = blockIdx.x * 256 + threadIdx.x;
    int node = gid >> 6;
    int lane = gid & 63;
    int beg = __builtin_amdgcn_readfirstlane(rbeg[node]);
    int end = beg + __builtin_amdgcn_readfirstlane(rlen[node]);
    double a0 = 0.0, a1 = 0.0, a2 = 0.0, a3 = 0.0;
    for (int j = beg; j < end; j += 16) {
        int4 i0 = *(const int4*)&csr2[j];
        int4 i1 = *(const int4*)&csr2[j + 4];
        int4 i2 = *(const int4*)&csr2[j + 8];
        int4 i3 = *(const int4*)&csr2[j + 12];
        float v0  = h2s[(size_t)(unsigned)i0.x * DD + lane];
        float v1  = h2s[(size_t)(unsigned)i0.y * DD + lane];
        float v2  = h2s[(size_t)(unsigned)i0.z * DD + lane];
        float v3  = h2s[(size_t)(unsigned)i0.w * DD + lane];
        float v4  = h2s[(size_t)(unsigned)i1.x * DD + lane];
        float v5  = h2s[(size_t)(unsigned)i1.y * DD + lane];
        float v6  = h2s[(size_t)(unsigned)i1.z * DD + lane];
        float v7  = h2s[(size_t)(unsigned)i1.w * DD + lane];
        float v8  = h2s[(size_t)(unsigned)i2.x * DD + lane];
        float v9  = h2s[(size_t)(unsigned)i2.y * DD + lane];
        float v10 = h2s[(size_t)(unsigned)i2.z * DD + lane];
        float v11 = h2s[(size_t)(unsigned)i2.w * DD + lane];
        float v12 = h2s[(size_t)(unsigned)i3.x * DD + lane];
        float v13 = h2s[(size_t)(unsigned)i3.y * DD + lane];
        float v14 = h2s[(size_t)(unsigned)i3.z * DD + lane];
        float v15 = h2s[(size_t)(unsigned)i3.w * DD + lane];
        a0 += (double)v0;  a1 += (double)v1;  a2 += (double)v2;  a3 += (double)v3;
        a0 += (double)v4;  a1 += (double)v5;  a2 += (double)v6;  a3 += (double)v7;
        a0 += (double)v8;  a1 += (double)v9;  a2 += (double)v10; a3 += (double)v11;
        a0 += (double)v12; a1 += (double)v13; a2 += (double)v14; a3 += (double)v15;
    }
    double sum = (a0 + a1) + (a2 + a3);
    float vf = (float)(dis[node] * sum + (double)b[lane]);
    if (apply_elu && vf <= 0.f) vf = expm1f(vf);
    out[gid] = vf;
}

// ---------------- launch ----------------

static inline size_t align256(size_t x) { return (x + 255) & ~(size_t)255; }

extern "C" void kernel_launch(void* const* d_in, const int* in_sizes, int n_in,
                              void* d_out, int out_size, void* d_ws, size_t ws_size,
                              hipStream_t stream) {
    const float* x  = (const float*)d_in[0];
    const int*   ei = (const int*)d_in[1];
    const float* W1 = (const float*)d_in[3];
    const float* b1 = (const float*)d_in[4];
    const float* W2 = (const float*)d_in[5];
    const float* b2 = (const float*)d_in[6];
    const float* W3 = (const float*)d_in[7];
    const float* b3 = (const float*)d_in[8];
    const float* W4 = (const float*)d_in[9];
    const float* b4 = (const float*)d_in[10];
    float* out = (float*)d_out;

    char* ws = (char*)d_ws;
    size_t off = 0;
    float*  h2s  = (float*) (ws + off); off = align256(off + (size_t)(NN + 1) * DD * sizeof(float));
    float*  A    = (float*) (ws + off); off = align256(off + (size_t)NN * DD * sizeof(float));
    double* dis  = (double*)(ws + off); off = align256(off + (size_t)NN * sizeof(double));
    int*    rbeg = (int*)   (ws + off); off = align256(off + (size_t)NN * sizeof(int));
    int*    rlen = (int*)   (ws + off); off = align256(off + (size_t)NN * sizeof(int));
    int*    bcur = (int*)   (ws + off); off = align256(off + (size_t)(NBKT + 1) * sizeof(int));
    int*    gcur = (int*)   (ws + off); off = align256(off + 256 * sizeof(int));
    int*    bkt  = (int*)   (ws + off); off = align256(off + (size_t)NBKT * BCAP * sizeof(int));
    int*    csr2 = (int*)   (ws + off); off = align256(off + (size_t)CSR2_CAP * sizeof(int));

    k_zero <<<1, 256, 0, stream>>>(bcur, gcur, h2s);
    k_bscat<<<NCH, 256, 0, stream>>>(ei, bcur, bkt);
    k_merge<<<NBKT, 256, 0, stream>>>(bcur, bkt, gcur, rbeg, rlen, dis, csr2);

    struct Layer { const float* in; const float* W; const float* b; float* o; int elu; };
    Layer L[4] = {
        { x,   W1, b1, A,   1 },
        { A,   W2, b2, out, 1 },
        { out, W3, b3, A,   1 },
        { A,   W4, b4, out, 0 },
    };

    const int NGB = (NN + 63) / 64;   // 1563
    for (int l = 0; l < 4; ++l) {
        k_gemm<<<NGB, 256, 0, stream>>>(L[l].in, L[l].W, dis, h2s);
        k_aggr<<<NN / 4, 256, 0, stream>>>(rbeg, rlen, csr2, h2s, dis,
                                           L[l].b, L[l].o, L[l].elu);
    }
}

// Round 14
// 369.620 us; speedup vs baseline: 1.1421x; 1.1421x over previous
//
#include <hip/hip_runtime.h>

#define NN 100000
#define NE 1600000
#define DD 64
#define BSH 9
#define BSZ 512                          // nodes per bucket
#define NBKT 196                         // ceil(NN/512)
#define BCAP 16384                       // bkt row capacity (mean 8163, ~91 sigma margin)
#define CHUNK 8192                       // edges per scatter block
#define NCH ((NE + CHUNK - 1) / CHUNK)   // 196
#define CSR2_CAP (NE + 16 * NN + 1024)   // sum of pad16(deg+1)

// ---------------- zero init ----------------

__global__ void k_zero(int* __restrict__ bcur, int* __restrict__ gcur,
                       float* __restrict__ h2s) {
    int t = threadIdx.x;
    if (t < NBKT) bcur[t] = 0;
    if (t == 255) *gcur = 0;
    if (t < DD) h2s[(size_t)NN * DD + t] = 0.f;   // dummy row = 0
}

// ---------------- P1: scatter edges into fixed-cap bucket rows ----------------
// packed = s | (dlocal << 17);  s < 2^17, dlocal < 512. bcur[b] ends as count.

__global__ __launch_bounds__(256) void k_bscat(const int* __restrict__ ei,
                                               int* __restrict__ bcur,
                                               int* __restrict__ bkt) {
    __shared__ int h[NBKT], rbase[NBKT], rcur[NBKT];
    int t = threadIdx.x;
    for (int i = t; i < NBKT; i += 256) h[i] = 0;
    __syncthreads();
    int cb = blockIdx.x * CHUNK;
    int s[32], d[32];
#pragma unroll
    for (int i = 0; i < 32; ++i) {
        int e = cb + t + 256 * i;
        if (e < NE) {
            s[i] = ei[e];
            d[i] = ei[NE + e];
            atomicAdd(&h[d[i] >> BSH], 1);
        } else {
            d[i] = -1;
        }
    }
    __syncthreads();
    for (int i = t; i < NBKT; i += 256) {
        int c = h[i];
        rbase[i] = c ? atomicAdd(&bcur[i], c) : 0;
        rcur[i] = 0;
    }
    __syncthreads();
#pragma unroll
    for (int i = 0; i < 32; ++i) {
        if (d[i] >= 0) {
            int b = d[i] >> BSH;
            int pos = rbase[b] + atomicAdd(&rcur[b], 1);
            bkt[(size_t)b * BCAP + pos] = s[i] | ((d[i] & (BSZ - 1)) << 17);
        }
    }
}

// ---------------- P2: per-bucket count + scan + atomic space reservation + csr2 fill ----
// One block per bucket. csr2 space reserved with one atomicAdd(gcur) per bucket;
// per-node rbeg/rlen recorded (bucket order in csr2 is irrelevant to aggr).

__global__ __launch_bounds__(256) void k_merge(const int* __restrict__ bcur,
                                               const int* __restrict__ bkt,
                                               int* __restrict__ gcur,
                                               int* __restrict__ rbeg,
                                               int* __restrict__ rlen,
                                               double* __restrict__ dis,
                                               int* __restrict__ csr2) {
    __shared__ int cnt[BSZ];
    __shared__ int cur[BSZ];
    __shared__ int s2[256];
    __shared__ int sbase;
    int b = blockIdx.x, t = threadIdx.x;
    cnt[t] = 0; cnt[t + 256] = 0;
    __syncthreads();
    int ec = bcur[b];
    const int* row = bkt + (size_t)b * BCAP;
    for (int j = t; j < ec; j += 256)
        atomicAdd(&cnt[row[j] >> 17], 1);
    __syncthreads();
    int nb = b * BSZ;
    int n0 = nb + 2 * t, n1 = nb + 2 * t + 1;
    int c0 = (n0 < NN) ? cnt[2 * t] : -1;
    int c1 = (n1 < NN) ? cnt[2 * t + 1] : -1;
    int q0 = (c0 >= 0) ? ((c0 + 16) & ~15) : 0;      // pad16(deg+1)
    int q1 = (c1 >= 0) ? ((c1 + 16) & ~15) : 0;
    s2[t] = q0 + q1;
    __syncthreads();
    for (int o = 1; o < 256; o <<= 1) {              // Hillis-Steele inclusive scan
        int v = (t >= o) ? s2[t - o] : 0;
        __syncthreads();
        s2[t] += v;
        __syncthreads();
    }
    if (t == 255) sbase = atomicAdd(gcur, s2[255]);  // reserve csr2 space
    __syncthreads();
    int base = sbase;
    int ex = s2[t] - (q0 + q1);                      // exclusive offset of node n0
    if (c0 >= 0) {
        rbeg[n0] = base + ex; rlen[n0] = q0;
        dis[n0] = 1.0 / sqrt((double)(c0 + 1));
        csr2[base + ex] = n0;                        // self entry
        cur[2 * t] = ex + 1;
    }
    if (c1 >= 0) {
        rbeg[n1] = base + ex + q0; rlen[n1] = q1;
        dis[n1] = 1.0 / sqrt((double)(c1 + 1));
        csr2[base + ex + q0] = n1;
        cur[2 * t + 1] = ex + q0 + 1;
    }
    __syncthreads();
    for (int j = t; j < ec; j += 256) {
        int pk = row[j];
        int pos = base + atomicAdd(&cur[pk >> 17], 1);
        csr2[pos] = pk & 0x1FFFF;
    }
    __syncthreads();
    if (c0 >= 0) { int e0 = ex + q0;      for (int j = cur[2 * t];     j < e0; ++j) csr2[base + j] = NN; }
    if (c1 >= 0) { int e1 = ex + q0 + q1; for (int j = cur[2 * t + 1]; j < e1; ++j) csr2[base + j] = NN; }
}

// ---------------- GEMM: h2s = (in @ W) * dis[row] ----------------
// 128 rows/block; thread t: rows (t>>3)*4..+3, cols (t&7)*8..+7. sIn padded to 65.
// 2-way k-split f32 accumulators; f64 only for the final dis scale.

__global__ __launch_bounds__(256) void k_gemm(const float* __restrict__ in,
                                              const float* __restrict__ W,
                                              const double* __restrict__ dis,
                                              float* __restrict__ h2s) {
    __shared__ float sW[DD * DD];
    __shared__ float sIn[128 * 65];
    int t = threadIdx.x;
    int brow = blockIdx.x * 128;
#pragma unroll
    for (int i = 0; i < 16; ++i) sW[t + 256 * i] = W[t + 256 * i];
#pragma unroll
    for (int i = 0; i < 32; ++i) {
        int idx = t + 256 * i;
        int rr = idx >> 6, kk = idx & 63;
        int gr = brow + rr; if (gr >= NN) gr = NN - 1;
        sIn[rr * 65 + kk] = in[(size_t)gr * DD + kk];
    }
    __syncthreads();
    int cg = t & 7;
    int rg = t >> 3;
    const float* sInB = &sIn[rg * 4 * 65];

    float aE[4][8], aO[4][8];
#pragma unroll
    for (int i = 0; i < 4; ++i)
#pragma unroll
        for (int j = 0; j < 8; ++j) { aE[i][j] = 0.f; aO[i][j] = 0.f; }

#pragma unroll 4
    for (int k = 0; k < DD; k += 2) {
        float4 w0 = *(const float4*)&sW[k * DD + cg * 8];
        float4 w1 = *(const float4*)&sW[k * DD + cg * 8 + 4];
        float4 w2 = *(const float4*)&sW[(k + 1) * DD + cg * 8];
        float4 w3 = *(const float4*)&sW[(k + 1) * DD + cg * 8 + 4];
        float wv0[8] = {w0.x, w0.y, w0.z, w0.w, w1.x, w1.y, w1.z, w1.w};
        float wv1[8] = {w2.x, w2.y, w2.z, w2.w, w3.x, w3.y, w3.z, w3.w};
#pragma unroll
        for (int i = 0; i < 4; ++i) {
            float a0 = sInB[i * 65 + k];
            float a1 = sInB[i * 65 + k + 1];
#pragma unroll
            for (int j = 0; j < 8; ++j) {
                aE[i][j] = fmaf(a0, wv0[j], aE[i][j]);
                aO[i][j] = fmaf(a1, wv1[j], aO[i][j]);
            }
        }
    }

#pragma unroll
    for (int i = 0; i < 4; ++i) {
        int row = brow + rg * 4 + i;
        if (row < NN) {
            double dr = dis[row];
            float o[8];
#pragma unroll
            for (int j = 0; j < 8; ++j)
                o[j] = (float)((double)(aE[i][j] + aO[i][j]) * dr);
            *(float4*)&h2s[(size_t)row * DD + cg * 8]     = make_float4(o[0], o[1], o[2], o[3]);
            *(float4*)&h2s[(size_t)row * DD + cg * 8 + 4] = make_float4(o[4], o[5], o[6], o[7]);
        }
    }
}

// ---------------- gather-aggregate: lane = feature, 16 gathers in flight ----------------

__global__ __launch_bounds__(256) void k_aggr(const int* __restrict__ rbeg,
                                              const int* __restrict__ rlen,
                                              const int* __restrict__ csr2,
                                              const float* __restrict__ h2s,
                                              const double* __restrict__ dis,
                                              const float* __restrict__ b,
                                              float* __restrict__ out,
                                              int apply_elu) {
    int gid = blockIdx.x * 256 + threadIdx.x;
    int node = gid >> 6;
    int lane = gid & 63;
    int beg = __builtin_amdgcn_readfirstlane(rbeg[node]);
    int end = beg + __builtin_amdgcn_readfirstlane(rlen[node]);
    double a0 = 0.0, a1 = 0.0, a2 = 0.0, a3 = 0.0;
    for (int j = beg; j < end; j += 16) {
        int4 i0 = *(const int4*)&csr2[j];
        int4 i1 = *(const int4*)&csr2[j + 4];
        int4 i2 = *(const int4*)&csr2[j + 8];
        int4 i3 = *(const int4*)&csr2[j + 12];
        float v0  = h2s[(size_t)(unsigned)i0.x * DD + lane];
        float v1  = h2s[(size_t)(unsigned)i0.y * DD + lane];
        float v2  = h2s[(size_t)(unsigned)i0.z * DD + lane];
        float v3  = h2s[(size_t)(unsigned)i0.w * DD + lane];
        float v4  = h2s[(size_t)(unsigned)i1.x * DD + lane];
        float v5  = h2s[(size_t)(unsigned)i1.y * DD + lane];
        float v6  = h2s[(size_t)(unsigned)i1.z * DD + lane];
        float v7  = h2s[(size_t)(unsigned)i1.w * DD + lane];
        float v8  = h2s[(size_t)(unsigned)i2.x * DD + lane];
        float v9  = h2s[(size_t)(unsigned)i2.y * DD + lane];
        float v10 = h2s[(size_t)(unsigned)i2.z * DD + lane];
        float v11 = h2s[(size_t)(unsigned)i2.w * DD + lane];
        float v12 = h2s[(size_t)(unsigned)i3.x * DD + lane];
        float v13 = h2s[(size_t)(unsigned)i3.y * DD + lane];
        float v14 = h2s[(size_t)(unsigned)i3.z * DD + lane];
        float v15 = h2s[(size_t)(unsigned)i3.w * DD + lane];
        a0 += (double)v0;  a1 += (double)v1;  a2 += (double)v2;  a3 += (double)v3;
        a0 += (double)v4;  a1 += (double)v5;  a2 += (double)v6;  a3 += (double)v7;
        a0 += (double)v8;  a1 += (double)v9;  a2 += (double)v10; a3 += (double)v11;
        a0 += (double)v12; a1 += (double)v13; a2 += (double)v14; a3 += (double)v15;
    }
    double sum = (a0 + a1) + (a2 + a3);
    float vf = (float)(dis[node] * sum + (double)b[lane]);
    if (apply_elu && vf <= 0.f) vf = expm1f(vf);
    out[gid] = vf;
}

// ---------------- launch ----------------

static inline size_t align256(size_t x) { return (x + 255) & ~(size_t)255; }

extern "C" void kernel_launch(void* const* d_in, const int* in_sizes, int n_in,
                              void* d_out, int out_size, void* d_ws, size_t ws_size,
                              hipStream_t stream) {
    const float* x  = (const float*)d_in[0];
    const int*   ei = (const int*)d_in[1];
    const float* W1 = (const float*)d_in[3];
    const float* b1 = (const float*)d_in[4];
    const float* W2 = (const float*)d_in[5];
    const float* b2 = (const float*)d_in[6];
    const float* W3 = (const float*)d_in[7];
    const float* b3 = (const float*)d_in[8];
    const float* W4 = (const float*)d_in[9];
    const float* b4 = (const float*)d_in[10];
    float* out = (float*)d_out;

    char* ws = (char*)d_ws;
    size_t off = 0;
    float*  h2s  = (float*) (ws + off); off = align256(off + (size_t)(NN + 1) * DD * sizeof(float));
    float*  A    = (float*) (ws + off); off = align256(off + (size_t)NN * DD * sizeof(float));
    double* dis  = (double*)(ws + off); off = align256(off + (size_t)NN * sizeof(double));
    int*    rbeg = (int*)   (ws + off); off = align256(off + (size_t)NN * sizeof(int));
    int*    rlen = (int*)   (ws + off); off = align256(off + (size_t)NN * sizeof(int));
    int*    bcur = (int*)   (ws + off); off = align256(off + (size_t)(NBKT + 1) * sizeof(int));
    int*    gcur = (int*)   (ws + off); off = align256(off + 256 * sizeof(int));
    int*    bkt  = (int*)   (ws + off); off = align256(off + (size_t)NBKT * BCAP * sizeof(int));
    int*    csr2 = (int*)   (ws + off); off = align256(off + (size_t)CSR2_CAP * sizeof(int));

    k_zero <<<1, 256, 0, stream>>>(bcur, gcur, h2s);
    k_bscat<<<NCH, 256, 0, stream>>>(ei, bcur, bkt);
    k_merge<<<NBKT, 256, 0, stream>>>(bcur, bkt, gcur, rbeg, rlen, dis, csr2);

    struct Layer { const float* in; const float* W; const float* b; float* o; int elu; };
    Layer L[4] = {
        { x,   W1, b1, A,   1 },
        { A,   W2, b2, out, 1 },
        { out, W3, b3, A,   1 },
        { A,   W4, b4, out, 0 },
    };

    const int NGB = (NN + 127) / 128;   // 782
    for (int l = 0; l < 4; ++l) {
        k_gemm<<<NGB, 256, 0, stream>>>(L[l].in, L[l].W, dis, h2s);
        k_aggr<<<NN / 4, 256, 0, stream>>>(rbeg, rlen, csr2, h2s, dis,
                                           L[l].b, L[l].o, L[l].elu);
    }
}